// Round 6
// baseline (145.153 us; speedup 1.0000x reference)
//
#include <hip/hip_runtime.h>
#include <hip/hip_bf16.h>

#define B_    4
#define CIN   64
#define E_    75000
#define K_    5
#define COUT  128
#define KTOT  320   // K_*CIN
#define MROWS 128   // rows per block (8 waves x 16)
#define NBLK  586   // ceil(E_/MROWS)

typedef __attribute__((ext_vector_type(8))) short short8;
typedef __attribute__((ext_vector_type(4))) float f32x4;
typedef __attribute__((ext_vector_type(4))) unsigned int u32x4;

static __device__ __forceinline__ unsigned short f2bf(float f) {
    __hip_bfloat16 h = __float2bfloat16(f);
    union { __hip_bfloat16 h; unsigned short u; } cv; cv.h = h; return cv.u;
}
static __device__ __forceinline__ float bflo(unsigned int v) { return __uint_as_float(v << 16); }
static __device__ __forceinline__ float bfhi(unsigned int v) { return __uint_as_float(v & 0xffff0000u); }
// packed f32->bf16 RNE (1 VALU inst)
static __device__ __forceinline__ unsigned int cvtpk(float lo, float hi) {
    unsigned int r;
    asm("v_cvt_pk_bf16_f32 %0, %1, %2" : "=v"(r) : "v"(lo), "v"(hi));
    return r;
}

// ---------------- Kernel 1: x (B,CIN,E) f32 -> f (B,E,CIN) bf16 ----------------
__global__ __launch_bounds__(256) void transpose_kernel(const float* __restrict__ x,
                                                        unsigned short* __restrict__ f) {
    __shared__ float lds[64][65];
    const int b  = blockIdx.y;
    const int e0 = blockIdx.x * 64;
    const int tid = threadIdx.x;
    const int lane_e = tid & 63;
    const int cg = tid >> 6;
    const int egc = min(e0 + lane_e, E_ - 1);
    const float* xb = x + (size_t)b * CIN * E_;
#pragma unroll
    for (int i = 0; i < 16; ++i) {
        int c = cg * 16 + i;
        lds[lane_e][c] = __builtin_nontemporal_load(&xb[(size_t)c * E_ + egc]);
    }
    __syncthreads();
    const int e = tid >> 2;
    const int q = tid & 3;
    if (e0 + e < E_) {
        unsigned short tmp[16] __attribute__((aligned(16)));
#pragma unroll
        for (int i = 0; i < 16; ++i) tmp[i] = f2bf(lds[e][q * 16 + i]);
        unsigned short* dst = f + ((size_t)b * E_ + e0 + e) * CIN + q * 16;
        *(short8*)dst       = *(short8*)&tmp[0];
        *(short8*)(dst + 8) = *(short8*)&tmp[8];
    }
}

// ------- Kernel 2: W (COUT, KTOT) f32 -> fragment-ordered, GROUP-PERMUTED bf16 Wf -------
// G group order in meshconv: [self, sum13, d13, sum24, d24] -> original feature
// blocks {0,1,3,2,4}. frag t = (s*8 + nf)*64 + lane ;
// elem j = W[nf*16 + (lane&15)][perm[s>>1]*64 + (s&1)*32 + (lane>>4)*8 + j]
__global__ void wconv_kernel(const float* __restrict__ W, unsigned short* __restrict__ Wf) {
    int t = blockIdx.x * 256 + threadIdx.x;
    if (t >= 10 * 8 * 64) return;
    const int perm[5] = {0, 1, 3, 2, 4};
    int lane = t & 63;
    int fidx = (t >> 6) & 7;
    int s    = t >> 9;
    int row = fidx * 16 + (lane & 15);
    int col = perm[s >> 1] * 64 + (s & 1) * 32 + (lane >> 4) * 8;
    const float* src = W + (size_t)row * KTOT + col;
    unsigned short tmp[8] __attribute__((aligned(16)));
#pragma unroll
    for (int j = 0; j < 8; ++j) tmp[j] = f2bf(src[j]);
    *(short8*)(Wf + (size_t)t * 8) = *(short8*)tmp;
}

// ---------------- Kernel 3: gather-fused MFMA GEMM, B in LDS ----------------
// 512 threads = 8 waves x 16 rows. Wf (80 KB) staged to LDS once; one barrier.
// Composites built just-in-time inside the MFMA sequence -> peak VGPR ~115 (<128)
// so two blocks stay resident per CU and anti-phase load/compute.
static __device__ __forceinline__ short8 ldfrag(const unsigned short* __restrict__ base,
                                                unsigned int off_shorts) {
    return *(const short8*)(base + off_shorts);
}

static __device__ __forceinline__ void mk_sumdiff(short8 xa, short8 xb, short8& s8, short8& d8) {
    union U { short8 s; unsigned int u[4]; } ua, ub, us, ud;
    ua.s = xa; ub.s = xb;
#pragma unroll
    for (int i = 0; i < 4; ++i) {
        float al = bflo(ua.u[i]), ah = bfhi(ua.u[i]);
        float bl = bflo(ub.u[i]), bh = bfhi(ub.u[i]);
        us.u[i] = cvtpk(al + bl, ah + bh);
        ud.u[i] = cvtpk(al - bl, ah - bh) & 0x7fff7fffu;
    }
    s8 = us.s; d8 = ud.s;
}

__global__ __launch_bounds__(512, 4) void meshconv_kernel(
    const unsigned short* __restrict__ f, const int* __restrict__ em,
    const unsigned short* __restrict__ Wf, const float* __restrict__ bias,
    float* __restrict__ out) {
    __shared__ u32x4 Bs[5120];                   // 80 KB: all of Wf (group-permuted)

    const int tid  = threadIdx.x;
    const int w    = tid >> 6, lane = tid & 63;
    const int b    = blockIdx.y;
    const int e0w  = blockIdx.x * MROWS + w * 16;
    const int l15  = lane & 15, l4 = lane >> 4;
    const int er   = min(e0w + l15, E_ - 1);     // this lane's source row (clamped tail)

    const unsigned short* fb = f + (size_t)b * E_ * CIN;

    // ---- stage Wf -> LDS first (its ds_writes need not wait on the gathers) ----
    const u32x4* Wg = (const u32x4*)Wf;
#pragma unroll
    for (int i = 0; i < 10; ++i) Bs[i * 512 + tid] = Wg[i * 512 + tid];

    // ---- neighbor indices (k=0 is self by construction): 4 dword loads ----
    const int* emr = em + ((size_t)b * E_ + er) * K_;
    int i1 = emr[1], i2 = emr[2], i3 = emr[3], i4 = emr[4];

    // ---- all 10 raw-fragment gathers in flight (drained by the barrier) ----
    const unsigned int co = (unsigned int)(l4 * 8);
    short8 gS0 = ldfrag(fb, ((unsigned int)er << 6) + co);
    short8 gS1 = ldfrag(fb, ((unsigned int)er << 6) + 32 + co);
    short8 g1a = ldfrag(fb, ((unsigned int)i1 << 6) + co);
    short8 g1b = ldfrag(fb, ((unsigned int)i1 << 6) + 32 + co);
    short8 g3a = ldfrag(fb, ((unsigned int)i3 << 6) + co);
    short8 g3b = ldfrag(fb, ((unsigned int)i3 << 6) + 32 + co);
    short8 g2a = ldfrag(fb, ((unsigned int)i2 << 6) + co);
    short8 g2b = ldfrag(fb, ((unsigned int)i2 << 6) + 32 + co);
    short8 g4a = ldfrag(fb, ((unsigned int)i4 << 6) + co);
    short8 g4b = ldfrag(fb, ((unsigned int)i4 << 6) + 32 + co);

    __syncthreads();

    // ---- GEMM: 10 K-steps x 8 N-frags; composites built just-in-time ----
    const short8* Bl = (const short8*)Bs;
    f32x4 acc[8];
#pragma unroll
    for (int nf = 0; nf < 8; ++nf) acc[nf] = (f32x4){0.f, 0.f, 0.f, 0.f};

#define STEP(s, afrag)                                                                  \
    {                                                                                   \
        short8 a_ = (afrag);                                                            \
        _Pragma("unroll")                                                               \
        for (int nf = 0; nf < 8; ++nf) {                                                \
            short8 bfr = Bl[((s) * 8 + nf) * 64 + lane];                                \
            acc[nf] = __builtin_amdgcn_mfma_f32_16x16x32_bf16(a_, bfr, acc[nf], 0, 0, 0); \
        }                                                                               \
    }

    // group 0: self
    STEP(0, gS0)
    STEP(1, gS1)
    // groups 1-2: sum13 then |d13| (raws g1,g3 die here)
    {
        short8 s13a, d13a, s13b, d13b;
        mk_sumdiff(g1a, g3a, s13a, d13a);
        mk_sumdiff(g1b, g3b, s13b, d13b);
        STEP(2, s13a)
        STEP(3, s13b)
        STEP(4, d13a)
        STEP(5, d13b)
    }
    // groups 3-4: sum24 then |d24| (raws g2,g4 die here)
    {
        short8 s24a, d24a, s24b, d24b;
        mk_sumdiff(g2a, g4a, s24a, d24a);
        mk_sumdiff(g2b, g4b, s24b, d24b);
        STEP(6, s24a)
        STEP(7, s24b)
        STEP(8, d24a)
        STEP(9, d24b)
    }
#undef STEP

    // ---- epilogue: bias + direct NT stores; out (B, COUT, E), E%4==0 ----
    float* ob = out + (size_t)b * COUT * E_;
    const int erow = e0w + l4 * 4;
    if (erow < E_) {
#pragma unroll
        for (int nf = 0; nf < 8; ++nf) {
            int o = nf * 16 + l15;
            f32x4 v = acc[nf] + bias[o];
            __builtin_nontemporal_store(v, (f32x4*)(ob + (size_t)o * E_ + erow));
        }
    }
}

extern "C" void kernel_launch(void* const* d_in, const int* in_sizes, int n_in,
                              void* d_out, int out_size, void* d_ws, size_t ws_size,
                              hipStream_t stream) {
    const float* x    = (const float*)d_in[0];
    const int*   em   = (const int*)d_in[1];
    const float* W    = (const float*)d_in[2];
    const float* bias = (const float*)d_in[3];
    float* out = (float*)d_out;

    unsigned short* f  = (unsigned short*)d_ws;                 // B*E*64 bf16 = 38.4 MB
    unsigned short* Wf = f + (size_t)B_ * E_ * CIN;             // 80 KB fragment-ordered W

    dim3 gridT(1172, B_);
    transpose_kernel<<<gridT, 256, 0, stream>>>(x, f);
    wconv_kernel<<<20, 256, 0, stream>>>(W, Wf);
    dim3 gridM(NBLK, B_);
    meshconv_kernel<<<gridM, 512, 0, stream>>>(f, em, Wf, bias, out);
}

// Round 7
// 115.632 us; speedup vs baseline: 1.2553x; 1.2553x over previous
//
#include <hip/hip_runtime.h>
#include <hip/hip_bf16.h>

#define B_    4
#define CIN   64
#define E_    75000
#define K_    5
#define COUT  128
#define KTOT  320   // K_*CIN
#define MROWS 256   // rows per block (8 waves x 2 tiles x 16)
#define NBLK  293   // ceil(E_/MROWS)

typedef __attribute__((ext_vector_type(8))) short short8;
typedef __attribute__((ext_vector_type(4))) float f32x4;
typedef __attribute__((ext_vector_type(4))) unsigned int u32x4;

static __device__ __forceinline__ unsigned short f2bf(float f) {
    __hip_bfloat16 h = __float2bfloat16(f);
    union { __hip_bfloat16 h; unsigned short u; } cv; cv.h = h; return cv.u;
}
static __device__ __forceinline__ float bflo(unsigned int v) { return __uint_as_float(v << 16); }
static __device__ __forceinline__ float bfhi(unsigned int v) { return __uint_as_float(v & 0xffff0000u); }
// packed f32->bf16 RNE (1 VALU inst)
static __device__ __forceinline__ unsigned int cvtpk(float lo, float hi) {
    unsigned int r;
    asm("v_cvt_pk_bf16_f32 %0, %1, %2" : "=v"(r) : "v"(lo), "v"(hi));
    return r;
}

// ---------------- Kernel 1: x (B,CIN,E) f32 -> f (B,E,CIN) bf16 ----------------
__global__ __launch_bounds__(256) void transpose_kernel(const float* __restrict__ x,
                                                        unsigned short* __restrict__ f) {
    __shared__ float lds[64][65];
    const int b  = blockIdx.y;
    const int e0 = blockIdx.x * 64;
    const int tid = threadIdx.x;
    const int lane_e = tid & 63;
    const int cg = tid >> 6;
    const int egc = min(e0 + lane_e, E_ - 1);
    const float* xb = x + (size_t)b * CIN * E_;
#pragma unroll
    for (int i = 0; i < 16; ++i) {
        int c = cg * 16 + i;
        lds[lane_e][c] = __builtin_nontemporal_load(&xb[(size_t)c * E_ + egc]);
    }
    __syncthreads();
    const int e = tid >> 2;
    const int q = tid & 3;
    if (e0 + e < E_) {
        unsigned short tmp[16] __attribute__((aligned(16)));
#pragma unroll
        for (int i = 0; i < 16; ++i) tmp[i] = f2bf(lds[e][q * 16 + i]);
        unsigned short* dst = f + ((size_t)b * E_ + e0 + e) * CIN + q * 16;
        *(short8*)dst       = *(short8*)&tmp[0];
        *(short8*)(dst + 8) = *(short8*)&tmp[8];
    }
}

// ------- Kernel 2: W (COUT, KTOT) f32 -> fragment-ordered bf16 Wf (R4 layout) -------
// frag t = (s*8 + nf)*64 + lane ; elem j = W[nf*16 + (lane&15)][s*32 + (lane>>4)*8 + j]
__global__ void wconv_kernel(const float* __restrict__ W, unsigned short* __restrict__ Wf) {
    int t = blockIdx.x * 256 + threadIdx.x;
    if (t >= 10 * 8 * 64) return;
    int lane = t & 63;
    int fidx = (t >> 6) & 7;
    int s    = t >> 9;
    int row = fidx * 16 + (lane & 15);
    int col = s * 32 + (lane >> 4) * 8;
    const float* src = W + (size_t)row * KTOT + col;
    unsigned short tmp[8] __attribute__((aligned(16)));
#pragma unroll
    for (int j = 0; j < 8; ++j) tmp[j] = f2bf(src[j]);
    *(short8*)(Wf + (size_t)t * 8) = *(short8*)tmp;
}

// ---------------- Kernel 3: gather-fused MFMA GEMM, B in LDS, 2 row-tiles/wave ----------------
// 512 threads = 8 waves; each wave owns rows [w*16, w*16+16) and [128+w*16, ...) of a
// 256-row block. Each B-fragment ds_read feeds TWO mfma (acc0, acc1): halves LDS traffic.
static __device__ __forceinline__ short8 ldfrag(const unsigned short* __restrict__ base,
                                                unsigned int off_shorts) {
    return *(const short8*)(base + off_shorts);
}

static __device__ __forceinline__ void mk_sumdiff(short8 xa, short8 xb, short8& s8, short8& d8) {
    union U { short8 s; unsigned int u[4]; } ua, ub, us, ud;
    ua.s = xa; ub.s = xb;
#pragma unroll
    for (int i = 0; i < 4; ++i) {
        float al = bflo(ua.u[i]), ah = bfhi(ua.u[i]);
        float bl = bflo(ub.u[i]), bh = bfhi(ub.u[i]);
        us.u[i] = cvtpk(al + bl, ah + bh);
        ud.u[i] = cvtpk(al - bl, ah - bh) & 0x7fff7fffu;
    }
    s8 = us.s; d8 = ud.s;
}

__global__ __launch_bounds__(512, 4) void meshconv_kernel(
    const unsigned short* __restrict__ f, const int* __restrict__ em,
    const unsigned short* __restrict__ Wf, const float* __restrict__ bias,
    float* __restrict__ out) {
    __shared__ u32x4 Bs[5120];                   // 80 KB: all of Wf

    const int tid  = threadIdx.x;
    const int w    = tid >> 6, lane = tid & 63;
    const int b    = blockIdx.y;
    const int e0   = blockIdx.x * MROWS;
    const int l15  = lane & 15, l4 = lane >> 4;
    const int r0   = min(e0 + w * 16 + l15, E_ - 1);
    const int r1   = min(e0 + 128 + w * 16 + l15, E_ - 1);

    const unsigned short* fb = f + (size_t)b * E_ * CIN;

    // ---- stage Wf -> LDS (80 KB / 512 threads = 10 x 16B each) ----
    const u32x4* Wg = (const u32x4*)Wf;
#pragma unroll
    for (int i = 0; i < 10; ++i) Bs[i * 512 + tid] = Wg[i * 512 + tid];

    // ---- neighbor indices for both tiles (k=0 is self by construction) ----
    const int* emb = em + (size_t)b * E_ * K_;
    const int* emr0 = emb + (size_t)r0 * K_;
    const int* emr1 = emb + (size_t)r1 * K_;
    int p1 = emr0[1], p2 = emr0[2], p3 = emr0[3], p4 = emr0[4];
    int q1 = emr1[1], q2 = emr1[2], q3 = emr1[3], q4 = emr1[4];

    // ---- all 20 raw-fragment gathers in flight (drained by the barrier) ----
    const unsigned int co = (unsigned int)(l4 * 8);
    short8 aS0 = ldfrag(fb, ((unsigned int)r0 << 6) + co);
    short8 aS1 = ldfrag(fb, ((unsigned int)r0 << 6) + 32 + co);
    short8 a1a = ldfrag(fb, ((unsigned int)p1 << 6) + co);
    short8 a1b = ldfrag(fb, ((unsigned int)p1 << 6) + 32 + co);
    short8 a2a = ldfrag(fb, ((unsigned int)p2 << 6) + co);
    short8 a2b = ldfrag(fb, ((unsigned int)p2 << 6) + 32 + co);
    short8 a3a = ldfrag(fb, ((unsigned int)p3 << 6) + co);
    short8 a3b = ldfrag(fb, ((unsigned int)p3 << 6) + 32 + co);
    short8 a4a = ldfrag(fb, ((unsigned int)p4 << 6) + co);
    short8 a4b = ldfrag(fb, ((unsigned int)p4 << 6) + 32 + co);
    short8 bS0 = ldfrag(fb, ((unsigned int)r1 << 6) + co);
    short8 bS1 = ldfrag(fb, ((unsigned int)r1 << 6) + 32 + co);
    short8 b1a = ldfrag(fb, ((unsigned int)q1 << 6) + co);
    short8 b1b = ldfrag(fb, ((unsigned int)q1 << 6) + 32 + co);
    short8 b2a = ldfrag(fb, ((unsigned int)q2 << 6) + co);
    short8 b2b = ldfrag(fb, ((unsigned int)q2 << 6) + 32 + co);
    short8 b3a = ldfrag(fb, ((unsigned int)q3 << 6) + co);
    short8 b3b = ldfrag(fb, ((unsigned int)q3 << 6) + 32 + co);
    short8 b4a = ldfrag(fb, ((unsigned int)q4 << 6) + co);
    short8 b4b = ldfrag(fb, ((unsigned int)q4 << 6) + 32 + co);

    __syncthreads();

    // ---- composite A fragments, R4 feature order [e0, s13, s24, d13, d24] ----
    short8 A0[10], A1[10];
    A0[0] = aS0; A0[1] = aS1;
    mk_sumdiff(a1a, a3a, A0[2], A0[6]);
    mk_sumdiff(a1b, a3b, A0[3], A0[7]);
    mk_sumdiff(a2a, a4a, A0[4], A0[8]);
    mk_sumdiff(a2b, a4b, A0[5], A0[9]);
    A1[0] = bS0; A1[1] = bS1;
    mk_sumdiff(b1a, b3a, A1[2], A1[6]);
    mk_sumdiff(b1b, b3b, A1[3], A1[7]);
    mk_sumdiff(b2a, b4a, A1[4], A1[8]);
    mk_sumdiff(b2b, b4b, A1[5], A1[9]);

    // ---- GEMM: 10 K-steps x 8 N-frags; each B-frag read feeds both tiles ----
    const short8* Bl = (const short8*)Bs;
    f32x4 acc0[8], acc1[8];
#pragma unroll
    for (int nf = 0; nf < 8; ++nf) {
        acc0[nf] = (f32x4){0.f, 0.f, 0.f, 0.f};
        acc1[nf] = (f32x4){0.f, 0.f, 0.f, 0.f};
    }

#pragma unroll
    for (int s = 0; s < 10; ++s) {
#pragma unroll
        for (int nf = 0; nf < 8; ++nf) {
            short8 bfr = Bl[(s * 8 + nf) * 64 + lane];
            acc0[nf] = __builtin_amdgcn_mfma_f32_16x16x32_bf16(A0[s], bfr, acc0[nf], 0, 0, 0);
            acc1[nf] = __builtin_amdgcn_mfma_f32_16x16x32_bf16(A1[s], bfr, acc1[nf], 0, 0, 0);
        }
    }

    // ---- epilogue: bias + plain stores (L2 merges the 64B segments) ----
    float* ob = out + (size_t)b * COUT * E_;
    {
        const int erow = e0 + w * 16 + l4 * 4;
        if (erow < E_) {
#pragma unroll
            for (int nf = 0; nf < 8; ++nf) {
                int o = nf * 16 + l15;
                f32x4 v = acc0[nf] + bias[o];
                *(f32x4*)(ob + (size_t)o * E_ + erow) = v;
            }
        }
    }
    {
        const int erow = e0 + 128 + w * 16 + l4 * 4;
        if (erow < E_) {
#pragma unroll
            for (int nf = 0; nf < 8; ++nf) {
                int o = nf * 16 + l15;
                f32x4 v = acc1[nf] + bias[o];
                *(f32x4*)(ob + (size_t)o * E_ + erow) = v;
            }
        }
    }
}

extern "C" void kernel_launch(void* const* d_in, const int* in_sizes, int n_in,
                              void* d_out, int out_size, void* d_ws, size_t ws_size,
                              hipStream_t stream) {
    const float* x    = (const float*)d_in[0];
    const int*   em   = (const int*)d_in[1];
    const float* W    = (const float*)d_in[2];
    const float* bias = (const float*)d_in[3];
    float* out = (float*)d_out;

    unsigned short* f  = (unsigned short*)d_ws;                 // B*E*64 bf16 = 38.4 MB
    unsigned short* Wf = f + (size_t)B_ * E_ * CIN;             // 80 KB fragment-ordered W

    dim3 gridT(1172, B_);
    transpose_kernel<<<gridT, 256, 0, stream>>>(x, f);
    wconv_kernel<<<20, 256, 0, stream>>>(W, Wf);
    dim3 gridM(NBLK, B_);
    meshconv_kernel<<<gridM, 512, 0, stream>>>(f, em, Wf, bias, out);
}

// Round 8
// 92.007 us; speedup vs baseline: 1.5776x; 1.2568x over previous
//
#include <hip/hip_runtime.h>
#include <hip/hip_bf16.h>

#define B_    4
#define CIN   64
#define E_    75000
#define K_    5
#define COUT  128
#define KTOT  320   // K_*CIN
#define MROWS 128   // rows per block (8 waves x 16)
#define NBLK  586   // ceil(E_/MROWS)

typedef __attribute__((ext_vector_type(8))) short short8;
typedef __attribute__((ext_vector_type(4))) float f32x4;
typedef __attribute__((ext_vector_type(4))) unsigned int u32x4;

static __device__ __forceinline__ unsigned short f2bf(float f) {
    __hip_bfloat16 h = __float2bfloat16(f);
    union { __hip_bfloat16 h; unsigned short u; } cv; cv.h = h; return cv.u;
}
static __device__ __forceinline__ float bflo(unsigned int v) { return __uint_as_float(v << 16); }
static __device__ __forceinline__ float bfhi(unsigned int v) { return __uint_as_float(v & 0xffff0000u); }
// packed f32->bf16 RNE (1 VALU inst)
static __device__ __forceinline__ unsigned int cvtpk(float lo, float hi) {
    unsigned int r;
    asm("v_cvt_pk_bf16_f32 %0, %1, %2" : "=v"(r) : "v"(lo), "v"(hi));
    return r;
}

// ---------------- Kernel 1: x (B,CIN,E) f32 -> f (B,E,CIN) bf16 ----------------
__global__ __launch_bounds__(256) void transpose_kernel(const float* __restrict__ x,
                                                        unsigned short* __restrict__ f) {
    __shared__ float lds[64][65];
    const int b  = blockIdx.y;
    const int e0 = blockIdx.x * 64;
    const int tid = threadIdx.x;
    const int lane_e = tid & 63;
    const int cg = tid >> 6;
    const int egc = min(e0 + lane_e, E_ - 1);
    const float* xb = x + (size_t)b * CIN * E_;
#pragma unroll
    for (int i = 0; i < 16; ++i) {
        int c = cg * 16 + i;
        lds[lane_e][c] = __builtin_nontemporal_load(&xb[(size_t)c * E_ + egc]);
    }
    __syncthreads();
    const int e = tid >> 2;
    const int q = tid & 3;
    if (e0 + e < E_) {
        unsigned short tmp[16] __attribute__((aligned(16)));
#pragma unroll
        for (int i = 0; i < 16; ++i) tmp[i] = f2bf(lds[e][q * 16 + i]);
        unsigned short* dst = f + ((size_t)b * E_ + e0 + e) * CIN + q * 16;
        *(short8*)dst       = *(short8*)&tmp[0];
        *(short8*)(dst + 8) = *(short8*)&tmp[8];
    }
}

// ------- Kernel 2: W (COUT, KTOT) f32 -> fragment-ordered bf16 Wf -------
// frag t = (s*8 + nf)*64 + lane ; elem j = W[nf*16 + (lane&15)][s*32 + (lane>>4)*8 + j]
__global__ void wconv_kernel(const float* __restrict__ W, unsigned short* __restrict__ Wf) {
    int t = blockIdx.x * 256 + threadIdx.x;
    if (t >= 10 * 8 * 64) return;
    int lane = t & 63;
    int fidx = (t >> 6) & 7;
    int s    = t >> 9;
    int row = fidx * 16 + (lane & 15);
    int col = s * 32 + (lane >> 4) * 8;
    const float* src = W + (size_t)row * KTOT + col;
    unsigned short tmp[8] __attribute__((aligned(16)));
#pragma unroll
    for (int j = 0; j < 8; ++j) tmp[j] = f2bf(src[j]);
    *(short8*)(Wf + (size_t)t * 8) = *(short8*)tmp;
}

// ---------------- Kernel 3: gather-fused MFMA GEMM, B in LDS ----------------
// 512 threads = 8 waves x 16 rows. Wf (80 KB) staged to LDS once; one barrier.
// waves_per_eu(4,4): LDS caps occupancy at 2 blocks/CU (= 4 waves/EU) anyway, so
// pin the register allocator to that tier (<=128 VGPR) instead of letting it
// shrink to 64 and serialize the 20 in-flight loads.
static __device__ __forceinline__ short8 ldfrag(const unsigned short* __restrict__ base,
                                                unsigned int off_shorts) {
    return *(const short8*)(base + off_shorts);
}

static __device__ __forceinline__ void mk_sumdiff(short8 xa, short8 xb, short8& s8, short8& d8) {
    union U { short8 s; unsigned int u[4]; } ua, ub, us, ud;
    ua.s = xa; ub.s = xb;
#pragma unroll
    for (int i = 0; i < 4; ++i) {
        float al = bflo(ua.u[i]), ah = bfhi(ua.u[i]);
        float bl = bflo(ub.u[i]), bh = bfhi(ub.u[i]);
        us.u[i] = cvtpk(al + bl, ah + bh);
        ud.u[i] = cvtpk(al - bl, ah - bh) & 0x7fff7fffu;
    }
    s8 = us.s; d8 = ud.s;
}

__global__ __launch_bounds__(512)
__attribute__((amdgpu_waves_per_eu(4, 4)))
void meshconv_kernel(
    const unsigned short* __restrict__ f, const int* __restrict__ em,
    const unsigned short* __restrict__ Wf, const float* __restrict__ bias,
    float* __restrict__ out) {
    __shared__ u32x4 Bs[5120];                   // 80 KB: all of Wf

    const int tid  = threadIdx.x;
    const int w    = tid >> 6, lane = tid & 63;
    const int b    = blockIdx.y;
    const int e0w  = blockIdx.x * MROWS + w * 16;
    const int l15  = lane & 15, l4 = lane >> 4;
    const int er   = min(e0w + l15, E_ - 1);     // this lane's source row (clamped tail)

    const unsigned short* fb = f + (size_t)b * E_ * CIN;

    // ---- neighbor indices (k=0 is self by construction): 4 broadcast dwords ----
    const int* emr = em + ((size_t)b * E_ + er) * K_;
    int i1 = emr[1], i2 = emr[2], i3 = emr[3], i4 = emr[4];

    // ---- stage Wf -> LDS (80 KB / 512 threads = 10 x 16B each) ----
    const u32x4* Wg = (const u32x4*)Wf;
#pragma unroll
    for (int i = 0; i < 10; ++i) Bs[i * 512 + tid] = Wg[i * 512 + tid];

    // ---- 10 A-fragment gathers in flight (drained by the barrier below) ----
    const unsigned int co = (unsigned int)(l4 * 8);
    short8 gS0 = ldfrag(fb, ((unsigned int)er << 6) + co);
    short8 gS1 = ldfrag(fb, ((unsigned int)er << 6) + 32 + co);
    short8 g1a = ldfrag(fb, ((unsigned int)i1 << 6) + co);
    short8 g1b = ldfrag(fb, ((unsigned int)i1 << 6) + 32 + co);
    short8 g2a = ldfrag(fb, ((unsigned int)i2 << 6) + co);
    short8 g2b = ldfrag(fb, ((unsigned int)i2 << 6) + 32 + co);
    short8 g3a = ldfrag(fb, ((unsigned int)i3 << 6) + co);
    short8 g3b = ldfrag(fb, ((unsigned int)i3 << 6) + 32 + co);
    short8 g4a = ldfrag(fb, ((unsigned int)i4 << 6) + co);
    short8 g4b = ldfrag(fb, ((unsigned int)i4 << 6) + 32 + co);

    __syncthreads();

    // ---- composite A fragments ----
    short8 A[10];
    A[0] = gS0; A[1] = gS1;
    mk_sumdiff(g1a, g3a, A[2], A[6]);
    mk_sumdiff(g1b, g3b, A[3], A[7]);
    mk_sumdiff(g2a, g4a, A[4], A[8]);
    mk_sumdiff(g2b, g4b, A[5], A[9]);

    // ---- GEMM: 10 K-steps x 8 N-frags, B from LDS ----
    const short8* Bl = (const short8*)Bs;
    f32x4 acc[8];
#pragma unroll
    for (int nf = 0; nf < 8; ++nf) acc[nf] = (f32x4){0.f, 0.f, 0.f, 0.f};

#pragma unroll
    for (int s = 0; s < 10; ++s) {
#pragma unroll
        for (int nf = 0; nf < 8; ++nf) {
            short8 bfr = Bl[(s * 8 + nf) * 64 + lane];
            acc[nf] = __builtin_amdgcn_mfma_f32_16x16x32_bf16(A[s], bfr, acc[nf], 0, 0, 0);
        }
    }

    // ---- epilogue: bias + store; out (B, COUT, E). E%4==0 -> aligned f32x4 ----
    float* ob = out + (size_t)b * COUT * E_;
    const int erow = e0w + l4 * 4;
    if (erow < E_) {
#pragma unroll
        for (int nf = 0; nf < 8; ++nf) {
            int o = nf * 16 + l15;
            f32x4 v = acc[nf] + bias[o];
            *(f32x4*)(ob + (size_t)o * E_ + erow) = v;
        }
    }
}

extern "C" void kernel_launch(void* const* d_in, const int* in_sizes, int n_in,
                              void* d_out, int out_size, void* d_ws, size_t ws_size,
                              hipStream_t stream) {
    const float* x    = (const float*)d_in[0];
    const int*   em   = (const int*)d_in[1];
    const float* W    = (const float*)d_in[2];
    const float* bias = (const float*)d_in[3];
    float* out = (float*)d_out;

    unsigned short* f  = (unsigned short*)d_ws;                 // B*E*64 bf16 = 38.4 MB
    unsigned short* Wf = f + (size_t)B_ * E_ * CIN;             // 80 KB fragment-ordered W

    dim3 gridT(1172, B_);
    transpose_kernel<<<gridT, 256, 0, stream>>>(x, f);
    wconv_kernel<<<20, 256, 0, stream>>>(W, Wf);
    dim3 gridM(NBLK, B_);
    meshconv_kernel<<<gridM, 512, 0, stream>>>(f, em, Wf, bias, out);
}